// Round 9
// baseline (70488.110 us; speedup 1.0000x reference)
//
#include <hip/hip_runtime.h>

#define H      51
#define T_IN   512
#define T_TOT  576
#define PH     56            // fp16 row pitch (halfs)  -> 112 B, b128-aligned rows
#define PF     52            // fp32 row pitch (floats) -> 208 B, b128-aligned rows
#define NR     204           // rows per matrix (4 gates x 51)
// LDS bytes: 3 fp16 matrices (Whh1, Wih2, Whh2) + 2 fp32 matrices (Wih3, Whh3)
#define LDSB   (3 * NR * PH * 2 + 2 * NR * PF * 4)   // 68,544 + 84,864 = 153,408 B

typedef _Float16 h8 __attribute__((ext_vector_type(8)));

__device__ __forceinline__ float bf2f(unsigned short u) {
    return __uint_as_float(((unsigned int)u) << 16);
}
__device__ __forceinline__ unsigned short f2bf(float f) {
    unsigned int u = __float_as_uint(f);
    u += 0x7fffu + ((u >> 16) & 1u);
    return (unsigned short)(u >> 16);
}
__device__ __forceinline__ float wget(const void* p, int i, bool is16) {
    return is16 ? bf2f(((const unsigned short*)p)[i]) : ((const float*)p)[i];
}
__device__ __forceinline__ float rl(float v, int k) {
    return __uint_as_float((unsigned int)__builtin_amdgcn_readlane((int)__float_as_uint(v), k));
}
__device__ __forceinline__ float sigm(float x) {
    x = fminf(fmaxf(x, -30.f), 30.f);
    return 1.f / (1.f + __expf(-x));
}
__device__ __forceinline__ float tanh_f(float x) {
    x = fminf(fmaxf(x, -15.f), 15.f);
    float e = __expf(2.f * x);
    return (e - 1.f) / (e + 1.f);
}
__device__ __forceinline__ float f4e(float4 v, int i) {
    return i == 0 ? v.x : i == 1 ? v.y : i == 2 ? v.z : v.w;
}

// Round-9: ELEMENT-PER-WAVE, ZERO-BARRIER main loop.
// Nine experiments showed the k-split attractor (~3,056us) is bound by its
// barrier-delimited cross-wave exchange (6 barriers + LDS round-trips/step),
// with no register slack to restructure (128-VGPR cliff). This decomposition
// removes the exchange entirely: wave w owns batch elem e = blockIdx*4+w;
// lane j computes ALL 4 gates of row j (ILP=4-8 accumulator chains);
// h[j] lives in lane j; h[k] broadcasts are readlane -> the serial chain has
// NO barrier, NO LDS access, NO cross-wave dependency. Weights (every wave
// needs all k) live in LDS: Wih3/Whh3 fp32 (exact, closest to output),
// Whh1/Wih2/Whh2 fp16 (ULP ~3.4e-5 on |w|<=0.14; damped by >=1 sigmoid).
// fp16 FMAs written as (float)f16 * f32 + f32 -> v_fma_mix_f32.
// Grid 256 x 256 thr (4 waves, 1 elem each), 153.4 KB LDS -> 1 block/CU,
// 1 wave/SIMD: latency hidden by compiler prefetch (~200 free VGPRs), not TLP.
extern "C" __global__ void __launch_bounds__(256)
__attribute__((amdgpu_waves_per_eu(1, 1)))
lstm3_kernel(const void* g_in,  const void* g_Wih1, const void* g_Whh1,
             const void* g_bih1, const void* g_bhh1,
             const void* g_Wih2, const void* g_Whh2, const void* g_bih2, const void* g_bhh2,
             const void* g_Wih3, const void* g_Whh3, const void* g_bih3, const void* g_bhh3,
             const void* g_Wlin, const void* g_blin, void* g_out)
{
    extern __shared__ char smraw[];
    _Float16* W1h = (_Float16*)smraw;            // Whh1 fp16
    _Float16* W2i = W1h + NR * PH;               // Wih2 fp16
    _Float16* W2h = W2i + NR * PH;               // Whh2 fp16
    float*    W3i = (float*)(smraw + 3 * NR * PH * 2);  // Wih3 fp32
    float*    W3h = W3i + NR * PF;               // Whh3 fp32

    const int tid  = threadIdx.x;
    const int lane = tid & 63;
    const int wid  = tid >> 6;
    const int e    = blockIdx.x * 4 + wid;       // my batch element
    const int jeff = (lane < H) ? lane : (H - 1);

    // ---- dtype sniff (proven: resolves fp32 on this harness)
    bool is16 = true;
    {
        const unsigned short* p = (const unsigned short*)g_Wih1;
        for (int i = 0; i < 204; ++i) {
            float v = fabsf(bf2f(p[i]));
            if (!(v < 0.2f)) is16 = false;
        }
    }

    // ---- LDS staging (once; amortized over 576 steps)
    for (int i = tid; i < NR * PH; i += 256) {
        int r = i / PH, k = i - r * PH;
        bool v = (k < H);
        W1h[i] = v ? (_Float16)wget(g_Whh1, r * H + k, is16) : (_Float16)0.f;
        W2i[i] = v ? (_Float16)wget(g_Wih2, r * H + k, is16) : (_Float16)0.f;
        W2h[i] = v ? (_Float16)wget(g_Whh2, r * H + k, is16) : (_Float16)0.f;
    }
    for (int i = tid; i < NR * PF; i += 256) {
        int r = i / PF, k = i - r * PF;
        bool v = (k < H);
        W3i[i] = v ? wget(g_Wih3, r * H + k, is16) : 0.f;
        W3h[i] = v ? wget(g_Whh3, r * H + k, is16) : 0.f;
    }
    __syncthreads();      // the ONLY barrier in the kernel

    // ---- per-lane constants (row jeff of each gate)
    const float b1_0 = wget(g_bih1, 0*H+jeff, is16) + wget(g_bhh1, 0*H+jeff, is16);
    const float b1_1 = wget(g_bih1, 1*H+jeff, is16) + wget(g_bhh1, 1*H+jeff, is16);
    const float b1_2 = wget(g_bih1, 2*H+jeff, is16) + wget(g_bhh1, 2*H+jeff, is16);
    const float b1_3 = wget(g_bih1, 3*H+jeff, is16) + wget(g_bhh1, 3*H+jeff, is16);
    const float b2_0 = wget(g_bih2, 0*H+jeff, is16) + wget(g_bhh2, 0*H+jeff, is16);
    const float b2_1 = wget(g_bih2, 1*H+jeff, is16) + wget(g_bhh2, 1*H+jeff, is16);
    const float b2_2 = wget(g_bih2, 2*H+jeff, is16) + wget(g_bhh2, 2*H+jeff, is16);
    const float b2_3 = wget(g_bih2, 3*H+jeff, is16) + wget(g_bhh2, 3*H+jeff, is16);
    const float b3_0 = wget(g_bih3, 0*H+jeff, is16) + wget(g_bhh3, 0*H+jeff, is16);
    const float b3_1 = wget(g_bih3, 1*H+jeff, is16) + wget(g_bhh3, 1*H+jeff, is16);
    const float b3_2 = wget(g_bih3, 2*H+jeff, is16) + wget(g_bhh3, 2*H+jeff, is16);
    const float b3_3 = wget(g_bih3, 3*H+jeff, is16) + wget(g_bhh3, 3*H+jeff, is16);
    const float wi1_0 = wget(g_Wih1, 0*H+jeff, is16);
    const float wi1_1 = wget(g_Wih1, 1*H+jeff, is16);
    const float wi1_2 = wget(g_Wih1, 2*H+jeff, is16);
    const float wi1_3 = wget(g_Wih1, 3*H+jeff, is16);
    const float wlin  = (lane < H) ? wget(g_Wlin, lane, is16) : 0.f;
    const float blin  = wget(g_blin, 0, is16);

    // ---- per-lane row pointers (named; rule: no runtime-indexed arrays)
    const h8* R1_0 = (const h8*)(W1h + (0*H + jeff) * PH);
    const h8* R1_1 = (const h8*)(W1h + (1*H + jeff) * PH);
    const h8* R1_2 = (const h8*)(W1h + (2*H + jeff) * PH);
    const h8* R1_3 = (const h8*)(W1h + (3*H + jeff) * PH);
    const h8* R2i_0 = (const h8*)(W2i + (0*H + jeff) * PH);
    const h8* R2i_1 = (const h8*)(W2i + (1*H + jeff) * PH);
    const h8* R2i_2 = (const h8*)(W2i + (2*H + jeff) * PH);
    const h8* R2i_3 = (const h8*)(W2i + (3*H + jeff) * PH);
    const h8* R2h_0 = (const h8*)(W2h + (0*H + jeff) * PH);
    const h8* R2h_1 = (const h8*)(W2h + (1*H + jeff) * PH);
    const h8* R2h_2 = (const h8*)(W2h + (2*H + jeff) * PH);
    const h8* R2h_3 = (const h8*)(W2h + (3*H + jeff) * PH);
    const float4* R3i_0 = (const float4*)(W3i + (0*H + jeff) * PF);
    const float4* R3i_1 = (const float4*)(W3i + (1*H + jeff) * PF);
    const float4* R3i_2 = (const float4*)(W3i + (2*H + jeff) * PF);
    const float4* R3i_3 = (const float4*)(W3i + (3*H + jeff) * PF);
    const float4* R3h_0 = (const float4*)(W3h + (0*H + jeff) * PF);
    const float4* R3h_1 = (const float4*)(W3h + (1*H + jeff) * PF);
    const float4* R3h_2 = (const float4*)(W3h + (2*H + jeff) * PF);
    const float4* R3h_3 = (const float4*)(W3h + (3*H + jeff) * PF);

    float h1 = 0.f, h2 = 0.f, h3 = 0.f;    // lane j holds h[j]
    float c1 = 0.f, c2 = 0.f, c3 = 0.f;
    float xf = 0.f;

    const unsigned short* in16 = (const unsigned short*)g_in;
    const float*          in32 = (const float*)g_in;
    unsigned short* o16 = (unsigned short*)g_out + (size_t)e * T_TOT;
    float*          o32 = (float*)g_out + (size_t)e * T_TOT;

    // prefetch x(0)
    float xn = is16 ? bf2f(in16[(size_t)e * T_IN]) : in32[(size_t)e * T_IN];

#pragma clang loop unroll(disable)
    for (int t = 0; t < T_TOT; ++t) {
        float x = (t < T_IN) ? xn : xf;
        if (t + 1 < T_IN)    // prefetch next x (off the dependency chain)
            xn = is16 ? bf2f(in16[(size_t)e * T_IN + t + 1])
                      : in32[(size_t)e * T_IN + t + 1];

        // ------- layer 1: gates = b1 + Wih1*x + Whh1 @ h1 (fp16 LDS) -------
        float a0 = fmaf(wi1_0, x, b1_0);
        float a1 = fmaf(wi1_1, x, b1_1);
        float a2 = fmaf(wi1_2, x, b1_2);
        float a3 = fmaf(wi1_3, x, b1_3);
#pragma unroll
        for (int kb = 0; kb < 7; ++kb) {
            h8 u0 = R1_0[kb], u1 = R1_1[kb], u2 = R1_2[kb], u3 = R1_3[kb];
#pragma unroll
            for (int i = 0; i < 8; ++i) {
                float s = rl(h1, 8*kb + i);      // k>=51: weight=0, h finite
                a0 = fmaf((float)u0[i], s, a0);
                a1 = fmaf((float)u1[i], s, a1);
                a2 = fmaf((float)u2[i], s, a2);
                a3 = fmaf((float)u3[i], s, a3);
            }
        }
        {
            float i_ = sigm(a0), f_ = sigm(a1), g_ = tanh_f(a2), o_ = sigm(a3);
            c1 = f_ * c1 + i_ * g_;
            h1 = o_ * tanh_f(c1);
        }

        // ------- layer 2: gates = b2 + Wih2 @ h1 + Whh2 @ h2 (fp16 LDS) ----
        a0 = b2_0; a1 = b2_1; a2 = b2_2; a3 = b2_3;
#pragma unroll
        for (int kb = 0; kb < 7; ++kb) {
            h8 ui0 = R2i_0[kb], ui1 = R2i_1[kb], ui2 = R2i_2[kb], ui3 = R2i_3[kb];
            h8 uh0 = R2h_0[kb], uh1 = R2h_1[kb], uh2 = R2h_2[kb], uh3 = R2h_3[kb];
#pragma unroll
            for (int i = 0; i < 8; ++i) {
                int k = 8*kb + i;
                float s = rl(h1, k), r = rl(h2, k);
                a0 = fmaf((float)ui0[i], s, a0); a0 = fmaf((float)uh0[i], r, a0);
                a1 = fmaf((float)ui1[i], s, a1); a1 = fmaf((float)uh1[i], r, a1);
                a2 = fmaf((float)ui2[i], s, a2); a2 = fmaf((float)uh2[i], r, a2);
                a3 = fmaf((float)ui3[i], s, a3); a3 = fmaf((float)uh3[i], r, a3);
            }
        }
        {
            float i_ = sigm(a0), f_ = sigm(a1), g_ = tanh_f(a2), o_ = sigm(a3);
            c2 = f_ * c2 + i_ * g_;
            h2 = o_ * tanh_f(c2);
        }

        // ------- layer 3: gates = b3 + Wih3 @ h2 + Whh3 @ h3 (fp32 LDS) ----
        a0 = b3_0; a1 = b3_1; a2 = b3_2; a3 = b3_3;
#pragma unroll
        for (int b = 0; b < 13; ++b) {
            float4 vi0 = R3i_0[b], vi1 = R3i_1[b], vi2 = R3i_2[b], vi3 = R3i_3[b];
            float4 vh0 = R3h_0[b], vh1 = R3h_1[b], vh2 = R3h_2[b], vh3 = R3h_3[b];
#pragma unroll
            for (int i = 0; i < 4; ++i) {
                int k = 4*b + i;
                float s = rl(h2, k), r = rl(h3, k);
                a0 = fmaf(f4e(vi0,i), s, a0); a0 = fmaf(f4e(vh0,i), r, a0);
                a1 = fmaf(f4e(vi1,i), s, a1); a1 = fmaf(f4e(vh1,i), r, a1);
                a2 = fmaf(f4e(vi2,i), s, a2); a2 = fmaf(f4e(vh2,i), r, a2);
                a3 = fmaf(f4e(vi3,i), s, a3); a3 = fmaf(f4e(vh3,i), r, a3);
            }
        }
        {
            float i_ = sigm(a0), f_ = sigm(a1), g_ = tanh_f(a2), o_ = sigm(a3);
            c3 = f_ * c3 + i_ * g_;
            h3 = o_ * tanh_f(c3);
        }

        // ------- head: in-wave reduce (wlin=0 for lanes >= H) ---------------
        float hp = wlin * h3;
        hp += __shfl_xor(hp, 1, 64);  hp += __shfl_xor(hp, 2, 64);
        hp += __shfl_xor(hp, 4, 64);  hp += __shfl_xor(hp, 8, 64);
        hp += __shfl_xor(hp, 16, 64); hp += __shfl_xor(hp, 32, 64);
        float ov = hp + blin;
        xf = ov;                                 // feeds future phase, in-wave
        if (lane == 0) {
            if (is16) o16[t] = f2bf(ov);
            else      o32[t] = ov;
        }
    }
}

extern "C" void kernel_launch(void* const* d_in, const int* in_sizes, int n_in,
                              void* d_out, int out_size, void* d_ws, size_t ws_size,
                              hipStream_t stream) {
    (void)in_sizes; (void)n_in; (void)d_ws; (void)ws_size; (void)out_size;
    size_t shmem = LDSB;                     // 153,408 B -> 1 block/CU
    hipFuncSetAttribute((const void*)lstm3_kernel,
                        hipFuncAttributeMaxDynamicSharedMemorySize, (int)shmem);
    lstm3_kernel<<<dim3(256), dim3(256), shmem, stream>>>(
        d_in[0],  d_in[1],  d_in[2],  d_in[3],  d_in[4],
        d_in[5],  d_in[6],  d_in[7],  d_in[8],
        d_in[9],  d_in[10], d_in[11], d_in[12],
        d_in[13], d_in[14], d_out);
}

// Round 10
// 2739.976 us; speedup vs baseline: 25.7258x; 25.7258x over previous
//
#include <hip/hip_runtime.h>

#define H      51
#define T_IN   512
#define T_TOT  576
#define PH     56            // fp16 row pitch (halfs)  -> 112 B; (7j+kb)%8 slot spread => ~2/bank, free
#define PF     52            // fp32 row pitch (floats) -> 208 B; (5j+b)%8 slot spread  => ~2/bank, free
#define NR     204           // rows per matrix (4 gates x 51)
// LDS bytes: 3 fp16 matrices (Whh1, Wih2, Whh2) + 2 fp32 matrices (Wih3, Whh3)
#define LDSB   (3 * NR * PH * 2 + 2 * NR * PF * 4)   // 68,544 + 84,864 = 153,408 B

typedef _Float16 h8 __attribute__((ext_vector_type(8)));

__device__ __forceinline__ float bf2f(unsigned short u) {
    return __uint_as_float(((unsigned int)u) << 16);
}
__device__ __forceinline__ unsigned short f2bf(float f) {
    unsigned int u = __float_as_uint(f);
    u += 0x7fffu + ((u >> 16) & 1u);
    return (unsigned short)(u >> 16);
}
__device__ __forceinline__ float wget(const void* p, int i, bool is16) {
    return is16 ? bf2f(((const unsigned short*)p)[i]) : ((const float*)p)[i];
}
__device__ __forceinline__ float rl(float v, int k) {
    return __uint_as_float((unsigned int)__builtin_amdgcn_readlane((int)__float_as_uint(v), k));
}
__device__ __forceinline__ float sigm(float x) {
    x = fminf(fmaxf(x, -30.f), 30.f);
    return 1.f / (1.f + __expf(-x));
}
__device__ __forceinline__ float tanh_f(float x) {
    x = fminf(fmaxf(x, -15.f), 15.f);
    float e = __expf(2.f * x);
    return (e - 1.f) / (e + 1.f);
}
__device__ __forceinline__ float f4e(float4 v, int i) {
    return i == 0 ? v.x : i == 1 ? v.y : i == 2 ? v.z : v.w;
}
#define SBAR() __builtin_amdgcn_sched_barrier(0)

// Round-10: round-9's ELEMENT-PER-WAVE zero-barrier structure + register
// discipline. r9's 70ms was loop-invariant spill-reload (FETCH 32.6 GB,
// VGPR=256): unbounded hoisting of 188 h-independent LDS weight loads
// (~750 VGPR demand) + 20 x 64-bit pointers. Fixes, nothing else changed:
//  (1) 5 base pointers; gate/slot offsets are compile-time immediates folded
//      into ds_read offset: (saves ~30 VGPRs of address state);
//  (2) amdgpu_waves_per_eu(2,2): 256-reg cap -> scheduler stops hoisting at
//      the pressure limit instead of spilling (r9's (1,1) allowed 512);
//  (3) sched_barrier(0) fences between layers and mid-layer: any region holds
//      <=52 in-flight loads (<=208 VGPR) yet stays big enough (26-52
//      independent ds_reads) to hide the ~120cy LDS latency.
// Precision scheme r9-validated (absmax bit-identical to fp32 rounds):
// Whh1/Wih2/Whh2 fp16 LDS, Wih3/Whh3 fp32 LDS; fp16 FMAs -> v_fma_mix_f32.
// Grid 256 x 256 thr (4 waves, 1 elem/wave), 153.4 KB LDS, 1 wave/SIMD;
// serial chain has NO barrier / NO cross-wave dependency.
extern "C" __global__ void __launch_bounds__(256)
__attribute__((amdgpu_waves_per_eu(2, 2)))
lstm3_kernel(const void* g_in,  const void* g_Wih1, const void* g_Whh1,
             const void* g_bih1, const void* g_bhh1,
             const void* g_Wih2, const void* g_Whh2, const void* g_bih2, const void* g_bhh2,
             const void* g_Wih3, const void* g_Whh3, const void* g_bih3, const void* g_bhh3,
             const void* g_Wlin, const void* g_blin, void* g_out)
{
    extern __shared__ char smraw[];
    _Float16* W1h = (_Float16*)smraw;                   // Whh1 fp16
    _Float16* W2i = W1h + NR * PH;                      // Wih2 fp16
    _Float16* W2h = W2i + NR * PH;                      // Whh2 fp16
    float*    W3i = (float*)(smraw + 3 * NR * PH * 2);  // Wih3 fp32
    float*    W3h = W3i + NR * PF;                      // Whh3 fp32

    const int tid  = threadIdx.x;
    const int lane = tid & 63;
    const int wid  = tid >> 6;
    const int e    = blockIdx.x * 4 + wid;              // my batch element
    const int jeff = (lane < H) ? lane : (H - 1);

    // ---- dtype sniff (proven: resolves fp32 on this harness)
    bool is16 = true;
    {
        const unsigned short* p = (const unsigned short*)g_Wih1;
        for (int i = 0; i < 204; ++i) {
            float v = fabsf(bf2f(p[i]));
            if (!(v < 0.2f)) is16 = false;
        }
    }

    // ---- LDS staging (once; amortized over 576 steps)
    for (int i = tid; i < NR * PH; i += 256) {
        int r = i / PH, k = i - r * PH;
        bool v = (k < H);
        W1h[i] = v ? (_Float16)wget(g_Whh1, r * H + k, is16) : (_Float16)0.f;
        W2i[i] = v ? (_Float16)wget(g_Wih2, r * H + k, is16) : (_Float16)0.f;
        W2h[i] = v ? (_Float16)wget(g_Whh2, r * H + k, is16) : (_Float16)0.f;
    }
    for (int i = tid; i < NR * PF; i += 256) {
        int r = i / PF, k = i - r * PF;
        bool v = (k < H);
        W3i[i] = v ? wget(g_Wih3, r * H + k, is16) : 0.f;
        W3h[i] = v ? wget(g_Whh3, r * H + k, is16) : 0.f;
    }
    __syncthreads();      // the ONLY barrier in the kernel

    // ---- per-lane constants (row jeff of each gate)
    const float b1_0 = wget(g_bih1, 0*H+jeff, is16) + wget(g_bhh1, 0*H+jeff, is16);
    const float b1_1 = wget(g_bih1, 1*H+jeff, is16) + wget(g_bhh1, 1*H+jeff, is16);
    const float b1_2 = wget(g_bih1, 2*H+jeff, is16) + wget(g_bhh1, 2*H+jeff, is16);
    const float b1_3 = wget(g_bih1, 3*H+jeff, is16) + wget(g_bhh1, 3*H+jeff, is16);
    const float b2_0 = wget(g_bih2, 0*H+jeff, is16) + wget(g_bhh2, 0*H+jeff, is16);
    const float b2_1 = wget(g_bih2, 1*H+jeff, is16) + wget(g_bhh2, 1*H+jeff, is16);
    const float b2_2 = wget(g_bih2, 2*H+jeff, is16) + wget(g_bhh2, 2*H+jeff, is16);
    const float b2_3 = wget(g_bih2, 3*H+jeff, is16) + wget(g_bhh2, 3*H+jeff, is16);
    const float b3_0 = wget(g_bih3, 0*H+jeff, is16) + wget(g_bhh3, 0*H+jeff, is16);
    const float b3_1 = wget(g_bih3, 1*H+jeff, is16) + wget(g_bhh3, 1*H+jeff, is16);
    const float b3_2 = wget(g_bih3, 2*H+jeff, is16) + wget(g_bhh3, 2*H+jeff, is16);
    const float b3_3 = wget(g_bih3, 3*H+jeff, is16) + wget(g_bhh3, 3*H+jeff, is16);
    const float wi1_0 = wget(g_Wih1, 0*H+jeff, is16);
    const float wi1_1 = wget(g_Wih1, 1*H+jeff, is16);
    const float wi1_2 = wget(g_Wih1, 2*H+jeff, is16);
    const float wi1_3 = wget(g_Wih1, 3*H+jeff, is16);
    const float wlin  = (lane < H) ? wget(g_Wlin, lane, is16) : 0.f;
    const float blin  = wget(g_blin, 0, is16);

    // ---- 5 per-lane base pointers; everything else is immediate offsets
    const _Float16* R1  = W1h + jeff * PH;
    const _Float16* R2i = W2i + jeff * PH;
    const _Float16* R2h = W2h + jeff * PH;
    const float*    R3i = W3i + jeff * PF;
    const float*    R3h = W3h + jeff * PF;
#define H8(base, g, kb)  (*(const h8*)((base) + (g) * 51 * PH + (kb) * 8))
#define F4(base, g, b)   (*(const float4*)((base) + (g) * 51 * PF + (b) * 4))

    float h1 = 0.f, h2 = 0.f, h3 = 0.f;    // lane j holds h[j]
    float c1 = 0.f, c2 = 0.f, c3 = 0.f;
    float xf = 0.f;

    const unsigned short* in16 = (const unsigned short*)g_in;
    const float*          in32 = (const float*)g_in;
    unsigned short* o16 = (unsigned short*)g_out + (size_t)e * T_TOT;
    float*          o32 = (float*)g_out + (size_t)e * T_TOT;

    // prefetch x(0)
    float xn = is16 ? bf2f(in16[(size_t)e * T_IN]) : in32[(size_t)e * T_IN];

#pragma clang loop unroll(disable)
    for (int t = 0; t < T_TOT; ++t) {
        float x = (t < T_IN) ? xn : xf;
        if (t + 1 < T_IN)    // prefetch next x (off the dependency chain)
            xn = is16 ? bf2f(in16[(size_t)e * T_IN + t + 1])
                      : in32[(size_t)e * T_IN + t + 1];

        // ------- layer 1: gates = b1 + Wih1*x + Whh1 @ h1 (fp16 LDS) -------
        float a0 = fmaf(wi1_0, x, b1_0);
        float a1 = fmaf(wi1_1, x, b1_1);
        float a2 = fmaf(wi1_2, x, b1_2);
        float a3 = fmaf(wi1_3, x, b1_3);
#pragma unroll
        for (int kb = 0; kb < 7; ++kb) {
            h8 u0 = H8(R1, 0, kb), u1 = H8(R1, 1, kb);
            h8 u2 = H8(R1, 2, kb), u3 = H8(R1, 3, kb);
#pragma unroll
            for (int i = 0; i < 8; ++i) {
                float s = rl(h1, 8*kb + i);      // k>=51: weight=0, h finite
                a0 = fmaf((float)u0[i], s, a0);
                a1 = fmaf((float)u1[i], s, a1);
                a2 = fmaf((float)u2[i], s, a2);
                a3 = fmaf((float)u3[i], s, a3);
            }
        }
        {
            float i_ = sigm(a0), f_ = sigm(a1), g_ = tanh_f(a2), o_ = sigm(a3);
            c1 = f_ * c1 + i_ * g_;
            h1 = o_ * tanh_f(c1);
        }
        SBAR();   // layer fence: bounds in-flight loads, no cross-layer hoist

        // ------- layer 2: gates = b2 + Wih2 @ h1 + Whh2 @ h2 (fp16 LDS) ----
        a0 = b2_0; a1 = b2_1; a2 = b2_2; a3 = b2_3;
#pragma unroll
        for (int kb = 0; kb < 4; ++kb) {
            h8 ui0 = H8(R2i, 0, kb), ui1 = H8(R2i, 1, kb);
            h8 ui2 = H8(R2i, 2, kb), ui3 = H8(R2i, 3, kb);
            h8 uh0 = H8(R2h, 0, kb), uh1 = H8(R2h, 1, kb);
            h8 uh2 = H8(R2h, 2, kb), uh3 = H8(R2h, 3, kb);
#pragma unroll
            for (int i = 0; i < 8; ++i) {
                int k = 8*kb + i;
                float s = rl(h1, k), r = rl(h2, k);
                a0 = fmaf((float)ui0[i], s, a0); a0 = fmaf((float)uh0[i], r, a0);
                a1 = fmaf((float)ui1[i], s, a1); a1 = fmaf((float)uh1[i], r, a1);
                a2 = fmaf((float)ui2[i], s, a2); a2 = fmaf((float)uh2[i], r, a2);
                a3 = fmaf((float)ui3[i], s, a3); a3 = fmaf((float)uh3[i], r, a3);
            }
        }
        SBAR();   // mid-layer fence: pressure bound
#pragma unroll
        for (int kb = 4; kb < 7; ++kb) {
            h8 ui0 = H8(R2i, 0, kb), ui1 = H8(R2i, 1, kb);
            h8 ui2 = H8(R2i, 2, kb), ui3 = H8(R2i, 3, kb);
            h8 uh0 = H8(R2h, 0, kb), uh1 = H8(R2h, 1, kb);
            h8 uh2 = H8(R2h, 2, kb), uh3 = H8(R2h, 3, kb);
#pragma unroll
            for (int i = 0; i < 8; ++i) {
                int k = 8*kb + i;
                float s = rl(h1, k), r = rl(h2, k);
                a0 = fmaf((float)ui0[i], s, a0); a0 = fmaf((float)uh0[i], r, a0);
                a1 = fmaf((float)ui1[i], s, a1); a1 = fmaf((float)uh1[i], r, a1);
                a2 = fmaf((float)ui2[i], s, a2); a2 = fmaf((float)uh2[i], r, a2);
                a3 = fmaf((float)ui3[i], s, a3); a3 = fmaf((float)uh3[i], r, a3);
            }
        }
        {
            float i_ = sigm(a0), f_ = sigm(a1), g_ = tanh_f(a2), o_ = sigm(a3);
            c2 = f_ * c2 + i_ * g_;
            h2 = o_ * tanh_f(c2);
        }
        SBAR();

        // ------- layer 3: gates = b3 + Wih3 @ h2 + Whh3 @ h3 (fp32 LDS) ----
        a0 = b3_0; a1 = b3_1; a2 = b3_2; a3 = b3_3;
#pragma unroll
        for (int b = 0; b < 7; ++b) {
            float4 vi0 = F4(R3i, 0, b), vi1 = F4(R3i, 1, b);
            float4 vi2 = F4(R3i, 2, b), vi3 = F4(R3i, 3, b);
            float4 vh0 = F4(R3h, 0, b), vh1 = F4(R3h, 1, b);
            float4 vh2 = F4(R3h, 2, b), vh3 = F4(R3h, 3, b);
#pragma unroll
            for (int i = 0; i < 4; ++i) {
                int k = 4*b + i;
                float s = rl(h2, k), r = rl(h3, k);
                a0 = fmaf(f4e(vi0,i), s, a0); a0 = fmaf(f4e(vh0,i), r, a0);
                a1 = fmaf(f4e(vi1,i), s, a1); a1 = fmaf(f4e(vh1,i), r, a1);
                a2 = fmaf(f4e(vi2,i), s, a2); a2 = fmaf(f4e(vh2,i), r, a2);
                a3 = fmaf(f4e(vi3,i), s, a3); a3 = fmaf(f4e(vh3,i), r, a3);
            }
        }
        SBAR();   // mid-layer fence: pressure bound
#pragma unroll
        for (int b = 7; b < 13; ++b) {
            float4 vi0 = F4(R3i, 0, b), vi1 = F4(R3i, 1, b);
            float4 vi2 = F4(R3i, 2, b), vi3 = F4(R3i, 3, b);
            float4 vh0 = F4(R3h, 0, b), vh1 = F4(R3h, 1, b);
            float4 vh2 = F4(R3h, 2, b), vh3 = F4(R3h, 3, b);
#pragma unroll
            for (int i = 0; i < 4; ++i) {
                int k = 4*b + i;
                float s = rl(h2, k), r = rl(h3, k);
                a0 = fmaf(f4e(vi0,i), s, a0); a0 = fmaf(f4e(vh0,i), r, a0);
                a1 = fmaf(f4e(vi1,i), s, a1); a1 = fmaf(f4e(vh1,i), r, a1);
                a2 = fmaf(f4e(vi2,i), s, a2); a2 = fmaf(f4e(vh2,i), r, a2);
                a3 = fmaf(f4e(vi3,i), s, a3); a3 = fmaf(f4e(vh3,i), r, a3);
            }
        }
        {
            float i_ = sigm(a0), f_ = sigm(a1), g_ = tanh_f(a2), o_ = sigm(a3);
            c3 = f_ * c3 + i_ * g_;
            h3 = o_ * tanh_f(c3);
        }

        // ------- head: in-wave reduce (wlin=0 for lanes >= H) ---------------
        float hp = wlin * h3;
        hp += __shfl_xor(hp, 1, 64);  hp += __shfl_xor(hp, 2, 64);
        hp += __shfl_xor(hp, 4, 64);  hp += __shfl_xor(hp, 8, 64);
        hp += __shfl_xor(hp, 16, 64); hp += __shfl_xor(hp, 32, 64);
        float ov = hp + blin;
        xf = ov;                                 // feeds future phase, in-wave
        if (lane == 0) {
            if (is16) o16[t] = f2bf(ov);
            else      o32[t] = ov;
        }
    }
}

extern "C" void kernel_launch(void* const* d_in, const int* in_sizes, int n_in,
                              void* d_out, int out_size, void* d_ws, size_t ws_size,
                              hipStream_t stream) {
    (void)in_sizes; (void)n_in; (void)d_ws; (void)ws_size; (void)out_size;
    size_t shmem = LDSB;                     // 153,408 B -> 1 block/CU
    hipFuncSetAttribute((const void*)lstm3_kernel,
                        hipFuncAttributeMaxDynamicSharedMemorySize, (int)shmem);
    lstm3_kernel<<<dim3(256), dim3(256), shmem, stream>>>(
        d_in[0],  d_in[1],  d_in[2],  d_in[3],  d_in[4],
        d_in[5],  d_in[6],  d_in[7],  d_in[8],
        d_in[9],  d_in[10], d_in[11], d_in[12],
        d_in[13], d_in[14], d_out);
}